// Round 12
// baseline (599.664 us; speedup 1.0000x reference)
//
#include <hip/hip_runtime.h>
#include <hip/hip_bf16.h>
#include <math.h>

#define DIMC 768
#define NH   12
#define HDIM 64
#define NSEQ 2048
#define NB   2
#define LAMBDA_INIT 0.1f

typedef __attribute__((ext_vector_type(8))) short bf16x8;
typedef __attribute__((ext_vector_type(4))) float f32x4;
typedef unsigned short u16;

__device__ __forceinline__ u16 f2b(float f) {
    unsigned u = __float_as_uint(f);
    return (u16)((u + 0x7FFFu + ((u >> 16) & 1u)) >> 16);
}
__device__ __forceinline__ float b2f(u16 h) {
    return __uint_as_float((unsigned)h << 16);
}

// ---------------------------------------------------------------------------
// split x (fp32) -> hi/lo bf16 arrays (no transpose)
// ---------------------------------------------------------------------------
__global__ __launch_bounds__(256)
void split32(const float* __restrict__ x, u16* __restrict__ hi,
             u16* __restrict__ lo, int n4)
{
    for (int i = blockIdx.x * 256 + threadIdx.x; i < n4; i += gridDim.x * 256) {
        float4 v = ((const float4*)x)[i];
        ushort4 h, l;
        h.x = f2b(v.x); l.x = f2b(v.x - b2f(h.x));
        h.y = f2b(v.y); l.y = f2b(v.y - b2f(h.y));
        h.z = f2b(v.z); l.z = f2b(v.z - b2f(h.z));
        h.w = f2b(v.w); l.w = f2b(v.w - b2f(h.w));
        ((ushort4*)hi)[i] = h;
        ((ushort4*)lo)[i] = l;
    }
}

// ---------------------------------------------------------------------------
// transpose + split: src fp32 [R][C_ld] (cols c0..c0+gridX*64) -> dst [c][R] hi/lo
// ---------------------------------------------------------------------------
__global__ __launch_bounds__(256)
void tsplit(const float* __restrict__ src, int R, int C_ld,
            u16* __restrict__ dhi, u16* __restrict__ dlo)
{
    __shared__ float T[64][65];
    const int tid = threadIdx.x;
    const int c0 = blockIdx.x * 64, r0 = blockIdx.y * 64;
    const int row = tid >> 2, cq = (tid & 3) * 4;
#pragma unroll
    for (int it = 0; it < 4; ++it) {
        int col = cq + it * 16;
        float4 v = *(const float4*)&src[(size_t)(r0 + row) * C_ld + c0 + col];
        T[row][col+0] = v.x; T[row][col+1] = v.y;
        T[row][col+2] = v.z; T[row][col+3] = v.w;
    }
    __syncthreads();
    const int c = tid >> 2, rq = (tid & 3) * 4;
#pragma unroll
    for (int it = 0; it < 4; ++it) {
        int rr = rq + it * 16;
#pragma unroll
        for (int i = 0; i < 4; ++i) {
            float f = T[rr + i][c];
            u16 h = f2b(f);
            size_t o = (size_t)(c0 + c) * R + r0 + rr + i;
            dhi[o] = h;
            dlo[o] = f2b(f - b2f(h));
        }
    }
}

// ---------------------------------------------------------------------------
// 3-pass hi/lo split bf16 MFMA GEMM. V output now PRE-PACKED for attention:
// dword (((bh*32+kt)*64+d)*32 + j) = bf16(kv=2j) | bf16(kv=2j+1)<<16
// (pairs (kv,kv+1) live in the same thread's acc[..][r]).
// ---------------------------------------------------------------------------
template<int MODE>
__global__ __launch_bounds__(256)
void gemm_bf16(const u16* __restrict__ Ahi, const u16* __restrict__ Alo,
               const float* __restrict__ A32,
               const u16* __restrict__ Bhi, const u16* __restrict__ Blo,
               u16* __restrict__ Qo, u16* __restrict__ Ko,
               u16* __restrict__ Vhi, u16* __restrict__ Vlo,
               float* __restrict__ OUT,
               const float* __restrict__ rrms, const float* __restrict__ normw,
               const float* __restrict__ bias)
{
    __shared__ u16 AhS[128][40], AlS[128][40], BhS[128][40], BlS[128][40];
    const int tid = threadIdx.x;
    const int l = tid & 63, w = tid >> 6;
    const int wm = w >> 1, wn = w & 1;
    const int m0 = blockIdx.y * 128, n0 = blockIdx.x * 128;
    const int srow = tid >> 1, scg = (tid & 1) * 16;

    float rsc = 1.0f;
    if (MODE == 2) rsc = rrms[m0 + srow];

    f32x4 acc[4][4];
#pragma unroll
    for (int i = 0; i < 4; ++i)
#pragma unroll
        for (int j = 0; j < 4; ++j) acc[i][j] = (f32x4){0.f,0.f,0.f,0.f};

    for (int k0 = 0; k0 < DIMC; k0 += 32) {
        if (MODE < 2) {
            const u16* pa = Ahi + (size_t)(m0 + srow) * DIMC + k0 + scg;
            const u16* pl = Alo + (size_t)(m0 + srow) * DIMC + k0 + scg;
            *(bf16x8*)&AhS[srow][scg]     = *(const bf16x8*)pa;
            *(bf16x8*)&AhS[srow][scg + 8] = *(const bf16x8*)(pa + 8);
            *(bf16x8*)&AlS[srow][scg]     = *(const bf16x8*)pl;
            *(bf16x8*)&AlS[srow][scg + 8] = *(const bf16x8*)(pl + 8);
        } else {
            const float* pa = A32 + (size_t)(m0 + srow) * DIMC + k0 + scg;
            float4 v0 = *(const float4*)(pa);
            float4 v1 = *(const float4*)(pa + 4);
            float4 v2 = *(const float4*)(pa + 8);
            float4 v3 = *(const float4*)(pa + 12);
            float4 w0 = *(const float4*)(normw + k0 + scg);
            float4 w1 = *(const float4*)(normw + k0 + scg + 4);
            float4 w2 = *(const float4*)(normw + k0 + scg + 8);
            float4 w3 = *(const float4*)(normw + k0 + scg + 12);
            float vv[16] = {v0.x,v0.y,v0.z,v0.w, v1.x,v1.y,v1.z,v1.w,
                            v2.x,v2.y,v2.z,v2.w, v3.x,v3.y,v3.z,v3.w};
            float nn[16] = {w0.x,w0.y,w0.z,w0.w, w1.x,w1.y,w1.z,w1.w,
                            w2.x,w2.y,w2.z,w2.w, w3.x,w3.y,w3.z,w3.w};
#pragma unroll
            for (int i = 0; i < 16; ++i) {
                float f = vv[i] * rsc * nn[i];
                u16 h = f2b(f);
                AhS[srow][scg + i] = h;
                AlS[srow][scg + i] = f2b(f - b2f(h));
            }
        }
        {
            const u16* pb = Bhi + (size_t)(n0 + srow) * DIMC + k0 + scg;
            const u16* pl = Blo + (size_t)(n0 + srow) * DIMC + k0 + scg;
            *(bf16x8*)&BhS[srow][scg]     = *(const bf16x8*)pb;
            *(bf16x8*)&BhS[srow][scg + 8] = *(const bf16x8*)(pb + 8);
            *(bf16x8*)&BlS[srow][scg]     = *(const bf16x8*)pl;
            *(bf16x8*)&BlS[srow][scg + 8] = *(const bf16x8*)(pl + 8);
        }
        __syncthreads();

        bf16x8 ah[4], al[4], bh[4], bl[4];
#pragma unroll
        for (int i = 0; i < 4; ++i) {
            ah[i] = *(const bf16x8*)&AhS[wm*64 + i*16 + (l & 15)][(l >> 4) * 8];
            al[i] = *(const bf16x8*)&AlS[wm*64 + i*16 + (l & 15)][(l >> 4) * 8];
            bh[i] = *(const bf16x8*)&BhS[wn*64 + i*16 + (l & 15)][(l >> 4) * 8];
            bl[i] = *(const bf16x8*)&BlS[wn*64 + i*16 + (l & 15)][(l >> 4) * 8];
        }
#pragma unroll
        for (int mi = 0; mi < 4; ++mi)
#pragma unroll
            for (int ni = 0; ni < 4; ++ni) {
                acc[mi][ni] = __builtin_amdgcn_mfma_f32_16x16x32_bf16(ah[mi], bh[ni], acc[mi][ni], 0, 0, 0);
                acc[mi][ni] = __builtin_amdgcn_mfma_f32_16x16x32_bf16(ah[mi], bl[ni], acc[mi][ni], 0, 0, 0);
                acc[mi][ni] = __builtin_amdgcn_mfma_f32_16x16x32_bf16(al[mi], bh[ni], acc[mi][ni], 0, 0, 0);
            }
        __syncthreads();
    }

    // epilogue
#pragma unroll
    for (int mi = 0; mi < 4; ++mi) {
#pragma unroll
        for (int ni = 0; ni < 4; ++ni) {
            const int n = n0 + wn*64 + ni*16 + (l & 15);
            const int mbase = m0 + wm*64 + mi*16 + (l >> 4) * 4;
            if (MODE == 2) {
#pragma unroll
                for (int r = 0; r < 4; ++r)
                    OUT[(size_t)(mbase + r) * DIMC + n] = acc[mi][ni][r] + bias[n];
            } else {
                const int three = n / DIMC;           // uniform per fragment
                const int rem = n - three * DIMC;
                const int h = rem >> 6, d = rem & 63;
                if (three == 0) {
#pragma unroll
                    for (int r = 0; r < 4; ++r) {
                        const int m = mbase + r;
                        const int b_ = m >> 11, n_ = m & (NSEQ - 1);
                        Qo[((size_t)(b_*NH + h) * NSEQ + n_) * HDIM + d] =
                            f2b(acc[mi][ni][r] * 0.125f);
                    }
                } else if (three == 1) {
#pragma unroll
                    for (int r = 0; r < 4; ++r) {
                        const int m = mbase + r;
                        const int b_ = m >> 11, n_ = m & (NSEQ - 1);
                        Ko[((size_t)(b_*NH + h) * NSEQ + n_) * HDIM + d] =
                            f2b(acc[mi][ni][r]);
                    }
                } else {   // V: packed-pair layout (MODE 0 only)
#pragma unroll
                    for (int p = 0; p < 2; ++p) {
                        const float v0 = acc[mi][ni][2*p];
                        const float v1 = acc[mi][ni][2*p + 1];
                        const u16 h0 = f2b(v0), h1 = f2b(v1);
                        const u16 g0 = f2b(v0 - b2f(h0)), g1 = f2b(v1 - b2f(h1));
                        const int m = mbase + 2*p;
                        const int b_ = m >> 11, n_ = m & (NSEQ - 1);
                        const int kt = n_ >> 6, j = (n_ & 63) >> 1;
                        const size_t o =
                            (((size_t)(b_*NH + h) * 32 + kt) * 64 + d) * 32 + j;
                        ((unsigned*)Vhi)[o] = (unsigned)h0 | ((unsigned)h1 << 16);
                        ((unsigned*)Vlo)[o] = (unsigned)g0 | ((unsigned)g1 << 16);
                    }
                }
            }
        }
    }
}

// ---------------------------------------------------------------------------
// bf16-MFMA diff-attention v5: VALU-volume attack on the v4 structure.
//  - V arrives PRE-PACKED from gemm<0>: staging = 4 dword loads + 4
//    conflict-free dword LDS stores per thread (no pack arithmetic).
//  - pointer-bump prefetch addressing (no per-tile 64-bit recompute)
//  - T13 defer-max THR=8 (rescale only when a row max grows by >8)
//  - T5 s_setprio(1) around both MFMA clusters
// LDS layouts & all rounding points identical to the r10-validated kernel.
// ---------------------------------------------------------------------------
#define KVB 64
#define NT  (NSEQ / KVB)

__global__ __launch_bounds__(512)
void attn_mfma5(const u16* __restrict__ Q1, const u16* __restrict__ K1,
                const unsigned* __restrict__ VhiP, const unsigned* __restrict__ VloP,
                const u16* __restrict__ Q2, const u16* __restrict__ K2,
                const float* __restrict__ lam1, const float* __restrict__ lam2,
                float* __restrict__ out)
{
    __shared__ char SMEM[53248];
    u16*      K1s   = (u16*)SMEM;                       //  8 KB [64 kv][64 d] swz
    u16*      K2s   = (u16*)(SMEM + 8192);              //  8 KB
    unsigned* VtHiU = (unsigned*)(SMEM + 16384);        //  9 KB [64 d][36 dw]
    unsigned* VtLoU = (unsigned*)(SMEM + 25600);        //  9 KB
    unsigned* PsU   = (unsigned*)(SMEM + 34816);        // 18 KB [8 w][16 q][36 dw]

    const int tid = threadIdx.x;
    const int l = tid & 63, w = tid >> 6;
    const int branch = w >> 2;          // 0: attn1, 1: attn2
    const int g = w & 3;                // q-row group
    const int qt = blockIdx.x, bh = blockIdx.y;
    const int b = bh / NH, h = bh % NH;
    const size_t hoff = (size_t)bh * NSEQ * HDIM;

    // per-wave Q fragment (A layout) for its branch
    const u16* qbase = branch ? Q2 : Q1;
    const int qrow = qt * 64 + g * 16 + (l & 15);
    const u16* qp = qbase + hoff + (size_t)qrow * HDIM + ((l >> 4) * 8);
    bf16x8 qa[2];
    qa[0] = *(const bf16x8*)(qp);
    qa[1] = *(const bf16x8*)(qp + 32);

    f32x4 o[4];
    float m[4], ls[4];
#pragma unroll
    for (int i = 0; i < 4; ++i) {
        o[i] = (f32x4){0.f,0.f,0.f,0.f};
        m[i] = -INFINITY; ls[i] = 0.f;
    }

    // staging roles (512 threads) + bumped pointers
    const int sr  = tid >> 3;            // K: kv row 0..63
    const int scu = (tid & 7) * 8;       // K: d ushort 0..56
    const int swz = (sr & 7) << 4;
    const int vd0 = (tid >> 5) * 4;      // V: d rows vd0..vd0+3
    const int vj  = tid & 31;            // V: dword col (kv-pair)

    const u16* k1c = K1 + hoff + (size_t)sr * HDIM + scu;
    const u16* k2c = K2 + hoff + (size_t)sr * HDIM + scu;
    const unsigned* vhc = VhiP + ((size_t)bh * 32 * 64 + vd0) * 32 + vj;
    const unsigned* vlc = VloP + ((size_t)bh * 32 * 64 + vd0) * 32 + vj;

    bf16x8 pk1, pk2;
    unsigned pvh[4], pvl[4];

#define LOADREGS()                                                             \
    {                                                                          \
        pk1 = *(const bf16x8*)k1c;  k1c += KVB * HDIM;                         \
        pk2 = *(const bf16x8*)k2c;  k2c += KVB * HDIM;                         \
        pvh[0] = vhc[0];  pvh[1] = vhc[32]; pvh[2] = vhc[64]; pvh[3] = vhc[96];\
        pvl[0] = vlc[0];  pvl[1] = vlc[32]; pvl[2] = vlc[64]; pvl[3] = vlc[96];\
        vhc += 64 * 32;  vlc += 64 * 32;                                       \
    }

    LOADREGS()

    const char* kb = branch ? (const char*)K2s : (const char*)K1s;
    unsigned* pw = &PsU[w * 576];

    for (int kt = 0; kt < NT; ++kt) {
        __syncthreads();   // all waves done reading previous tile's LDS
        // ---- write prefetched K (swizzled b128) and V (dword, conflict-free) --
        *(bf16x8*)((char*)K1s + sr * 128 + ((scu * 2) ^ swz)) = pk1;
        *(bf16x8*)((char*)K2s + sr * 128 + ((scu * 2) ^ swz)) = pk2;
#pragma unroll
        for (int i = 0; i < 4; ++i) {
            VtHiU[(vd0 + i) * 36 + vj] = pvh[i];
            VtLoU[(vd0 + i) * 36 + vj] = pvl[i];
        }
        __syncthreads();   // staging complete

        if (kt + 1 < NT) LOADREGS()   // issue next tile's loads early

        // ---- S = Q K^T (own branch; 4 kv-subtiles x 2 K-halves) ----
        f32x4 s[4];
#pragma unroll
        for (int si = 0; si < 4; ++si) s[si] = (f32x4){0.f,0.f,0.f,0.f};
        const int xr = (l & 7) << 4;
        __builtin_amdgcn_s_setprio(1);
#pragma unroll
        for (int hf = 0; hf < 2; ++hf) {
            const int d0b = ((l >> 4) << 4) + (hf << 6);
#pragma unroll
            for (int si = 0; si < 4; ++si) {
                const int ra = si * 16 + (l & 15);
                bf16x8 kv = *(const bf16x8*)(kb + ra * 128 + (d0b ^ xr));
                s[si] = __builtin_amdgcn_mfma_f32_16x16x32_bf16(qa[hf], kv, s[si], 0, 0, 0);
            }
        }
        __builtin_amdgcn_s_setprio(0);

        // ---- online softmax (defer-max THR=8), Ps wave-private ----
#pragma unroll
        for (int r = 0; r < 4; ++r) {
            const int row = (l >> 4) * 4 + r;
            float rm = fmaxf(fmaxf(s[0][r], s[1][r]), fmaxf(s[2][r], s[3][r]));
#pragma unroll
            for (int mm = 1; mm < 16; mm <<= 1)
                rm = fmaxf(rm, __shfl_xor(rm, mm));
            if (__any(rm - m[r] > 8.0f)) {    // rare rescale path
                float mn = fmaxf(m[r], rm);
                float c = __expf(m[r] - mn);
                ls[r] *= c;  m[r] = mn;
#pragma unroll
                for (int dt = 0; dt < 4; ++dt) o[dt][r] *= c;
            }
            u16 hh[4];
            float rs = 0.f;
#pragma unroll
            for (int si = 0; si < 4; ++si) {
                hh[si] = f2b(__expf(s[si][r] - m[r]));
                rs += b2f(hh[si]);
            }
#pragma unroll
            for (int mm = 1; mm < 16; mm <<= 1)
                rs += __shfl_xor(rs, mm);
            ls[r] += rs;

            int xx[4];
#pragma unroll
            for (int si = 0; si < 4; ++si) xx[si] = __shfl_xor((int)hh[si], 1);
            const int u = l & 15;
            if ((l & 1) == 0) {
                pw[row*36 +      (u >> 1)] = (unsigned)hh[0] | ((unsigned)xx[0] << 16);
                pw[row*36 + 16 + (u >> 1)] = (unsigned)hh[2] | ((unsigned)xx[2] << 16);
            } else {
                pw[row*36 +  8 + (u >> 1)] = (unsigned)xx[1] | ((unsigned)hh[1] << 16);
                pw[row*36 + 24 + (u >> 1)] = (unsigned)xx[3] | ((unsigned)hh[3] << 16);
            }
        }
        // no barrier: Ps slice is wave-private

        // ---- O += P (Vhi + Vlo) over both kv-halves ----
        __builtin_amdgcn_s_setprio(1);
#pragma unroll
        for (int h2 = 0; h2 < 2; ++h2) {
            const int po = (l & 15) * 144 + h2 * 64 + ((l >> 4) << 4);
            bf16x8 pa = *(const bf16x8*)((const char*)pw + po);
#pragma unroll
            for (int dt = 0; dt < 4; ++dt) {
                const int vo = (dt * 16 + (l & 15)) * 144 + h2 * 64 + ((l >> 4) << 4);
                bf16x8 vhib = *(const bf16x8*)((const char*)VtHiU + vo);
                bf16x8 vlob = *(const bf16x8*)((const char*)VtLoU + vo);
                o[dt] = __builtin_amdgcn_mfma_f32_16x16x32_bf16(pa, vhib, o[dt], 0, 0, 0);
                o[dt] = __builtin_amdgcn_mfma_f32_16x16x32_bf16(pa, vlob, o[dt], 0, 0, 0);
            }
        }
        __builtin_amdgcn_s_setprio(0);
    }
#undef LOADREGS

    // ---- diff-combine epilogue through LDS overlay ----
    __syncthreads();                    // done with K/V LDS
    float* MRG = (float*)SMEM;          // [4 g][16 q][68 d-pad] = 17.4 KB
    if (branch == 1) {
        const float lam = lam1[h] - lam2[h] + LAMBDA_INIT;
#pragma unroll
        for (int r = 0; r < 4; ++r) {
            const float i2 = lam / ls[r];
            const int row = (l >> 4) * 4 + r;
#pragma unroll
            for (int dt = 0; dt < 4; ++dt)
                MRG[(g * 16 + row) * 68 + dt * 16 + (l & 15)] = o[dt][r] * i2;
        }
    }
    __syncthreads();
    if (branch == 0) {
#pragma unroll
        for (int r = 0; r < 4; ++r) {
            const float i1 = 1.0f / ls[r];
            const int row = (l >> 4) * 4 + r;
            const int q = qt * 64 + g * 16 + row;
            const size_t rowoff = (size_t)(b * NSEQ + q) * DIMC + h * HDIM;
#pragma unroll
            for (int dt = 0; dt < 4; ++dt)
                out[rowoff + dt * 16 + (l & 15)] =
                    o[dt][r] * i1 - MRG[(g * 16 + row) * 68 + dt * 16 + (l & 15)];
        }
    }
}

// ---------------------------------------------------------------------------
// Per-row 1/rms for RMSNorm (fused into proj GEMM A-load).
// ---------------------------------------------------------------------------
__global__ __launch_bounds__(256)
void rrms_kernel(const float* __restrict__ X, float* __restrict__ R)
{
    const int r = blockIdx.x;
    const int t = threadIdx.x;
    const float* row = X + (size_t)r * DIMC;
    float s = 0.f;
#pragma unroll
    for (int k = 0; k < 3; ++k) {
        float v = row[t + k * 256];
        s = fmaf(v, v, s);
    }
#pragma unroll
    for (int mm = 1; mm < 64; mm <<= 1) s += __shfl_xor(s, mm);
    __shared__ float wsum[4];
    if ((t & 63) == 0) wsum[t >> 6] = s;
    __syncthreads();
    if (t == 0) R[r] = rsqrtf((wsum[0]+wsum[1]+wsum[2]+wsum[3]) * (1.0f/DIMC) + 1e-6f);
}

// ---------------------------------------------------------------------------
extern "C" void kernel_launch(void* const* d_in, const int* in_sizes, int n_in,
                              void* d_out, int out_size, void* d_ws, size_t ws_size,
                              hipStream_t stream)
{
    const float* x   = (const float*)d_in[0];
    const float* Wq1 = (const float*)d_in[1];
    const float* Wq2 = (const float*)d_in[2];
    const float* Wp  = (const float*)d_in[3];
    const float* bp  = (const float*)d_in[4];
    const float* nw  = (const float*)d_in[5];
    const float* la1 = (const float*)d_in[6];
    const float* la2 = (const float*)d_in[7];
    float* out = (float*)d_out;

    const size_t HSZ = (size_t)NB * NH * NSEQ * HDIM;   // 3,145,728
    const size_t XSZ = (size_t)NB * NSEQ * DIMC;        // 3,145,728

    u16* p = (u16*)d_ws;
    u16* Q1b = p;  p += HSZ;
    u16* K1b = p;  p += HSZ;
    u16* Q2b = p;  p += HSZ;
    u16* K2b = p;  p += HSZ;
    u16* V1h = p;  p += HSZ;   // packed-pair dword layout (same byte size)
    u16* V1l = p;  p += HSZ;
    u16* xhi = p;  p += XSZ;
    u16* xlo = p;  p += XSZ;
    u16* W1th = p; p += (size_t)2304 * 768;
    u16* W1tl = p; p += (size_t)2304 * 768;
    u16* W2th = p; p += (size_t)1536 * 768;
    u16* W2tl = p; p += (size_t)1536 * 768;
    u16* Wpth = p; p += (size_t)768 * 768;
    u16* Wptl = p; p += (size_t)768 * 768;
    float* AO = (float*)p;
    float* RR = AO + XSZ;

    // input conversion
    split32<<<dim3(1024), 256, 0, stream>>>(x, xhi, xlo, (int)(XSZ / 4));
    tsplit<<<dim3(36, 12), 256, 0, stream>>>(Wq1, DIMC, 3*DIMC, W1th, W1tl);
    tsplit<<<dim3(24, 12), 256, 0, stream>>>(Wq2, DIMC, 3*DIMC, W2th, W2tl);
    tsplit<<<dim3(12, 12), 256, 0, stream>>>(Wp,  DIMC, DIMC,   Wpth, Wptl);

    // QKV projections (MFMA, 3-pass split)
    gemm_bf16<0><<<dim3(18, 32), 256, 0, stream>>>(xhi, xlo, nullptr, W1th, W1tl,
                                                   Q1b, K1b, V1h, V1l, nullptr,
                                                   nullptr, nullptr, nullptr);
    gemm_bf16<1><<<dim3(12, 32), 256, 0, stream>>>(xhi, xlo, nullptr, W2th, W2tl,
                                                   Q2b, K2b, nullptr, nullptr, nullptr,
                                                   nullptr, nullptr, nullptr);
    // diff attention (branch-split waves, packed V, defer-max, setprio)
    attn_mfma5<<<dim3(NSEQ/64, NB*NH), 512, 0, stream>>>(Q1b, K1b,
                                                         (const unsigned*)V1h,
                                                         (const unsigned*)V1l,
                                                         Q2b, K2b, la1, la2, AO);
    // RMSNorm stats
    rrms_kernel<<<dim3(NB*NSEQ), 256, 0, stream>>>(AO, RR);
    // out = RMSNorm(AO) @ W_proj + b_proj (MFMA, fold rrms*nw on A-load)
    gemm_bf16<2><<<dim3(6, 32), 256, 0, stream>>>(nullptr, nullptr, AO, Wpth, Wptl,
                                                  nullptr, nullptr, nullptr, nullptr,
                                                  out, RR, nw, bp);
}